// Round 18
// baseline (275.324 us; speedup 1.0000x reference)
//
#include <hip/hip_runtime.h>
#include <math.h>

typedef short short8 __attribute__((ext_vector_type(8)));
typedef float f32x4 __attribute__((ext_vector_type(4)));
typedef unsigned int uint4v __attribute__((ext_vector_type(4)));
typedef unsigned short ushort_t;

__device__ inline ushort_t f2bf(float f) {
    unsigned u = __builtin_bit_cast(unsigned, f);
    u = (u + 0x7fffu + ((u >> 16) & 1u)) >> 16;   // RNE
    return (ushort_t)u;
}
__device__ inline float bf2f(ushort_t u) {
    return __builtin_bit_cast(float, (unsigned)u << 16);
}
__device__ inline void gload_lds16(const ushort_t* g, short* l) {
    __builtin_amdgcn_global_load_lds((const __attribute__((address_space(1))) unsigned int*)g,
                                     (__attribute__((address_space(3))) unsigned int*)l, 16, 0, 0);
}

// ---------------- prep: all weight packs + zero page + both NHWC transposes, ONE launch ----------------
__device__ inline void wpack_body(const float* __restrict__ w, ushort_t* __restrict__ wpk,
                                  int COUT, int NF, int bidLocal, int tid) {
    int T = bidLocal * 256 + tid;
    int lane = T & 63;
    int rest = T >> 6;
    int n = rest % NF;
    int kstep = rest / NF;          // 0..71
    int t = kstep >> 3, cc = kstep & 7;
    int oc = n * 16 + (lane & 15);
    int kk = (lane >> 4) * 8;
    short8 sv;
#pragma unroll
    for (int j = 0; j < 8; ++j) {
        int ci = cc * 32 + kk + j;
        float val = (oc < COUT) ? w[((size_t)oc * 256 + ci) * 9 + t] : 0.f;
        sv[j] = (short)f2bf(val);
    }
    *(short8*)&wpk[(size_t)T * 8] = sv;
}

__global__ __launch_bounds__(256)
void prep_all_kernel(const float* w1, ushort_t* wpk1,
                     const float* w_off, ushort_t* wpkO,
                     const float* w_dcn, ushort_t* wpkD,
                     const float* w2, ushort_t* wpk2,
                     const float* w3, ushort_t* wpk3,
                     ushort_t* zp,
                     const float* __restrict__ votes, const float* __restrict__ x,
                     ushort_t* __restrict__ aN, ushort_t* __restrict__ xN) {
    __shared__ short s[64 * 66];
    int bid = blockIdx.x, tid = threadIdx.x;
    if (bid < 288)       { wpack_body(w1,    wpk1, 256, 16, bid,        tid); return; }
    else if (bid < 324)  { wpack_body(w_off, wpkO, 27,  2,  bid - 288,  tid); return; }
    else if (bid < 612)  { wpack_body(w_dcn, wpkD, 256, 16, bid - 324,  tid); return; }
    else if (bid < 900)  { wpack_body(w2,    wpk2, 256, 16, bid - 612,  tid); return; }
    else if (bid < 1188) { wpack_body(w3,    wpk3, 256, 16, bid - 900,  tid); return; }
    else if (bid == 1188) { zp[tid] = 0; return; }
    // nhwc transpose blocks
    int nb = bid - 1189;                  // 0..4095
    const int px0 = (nb & 255) * 64;
    const int ci0 = ((nb >> 8) & 3) * 64;
    const int z   = nb >> 10;             // 0,1 = votes(relu); 2,3 = x
    const int b   = z & 1;
    const bool doRelu = (z < 2);
    const float* inb = (doRelu ? votes : x) + (size_t)b * 256 * 16384;
    ushort_t* ob = (doRelu ? aN : xN) + (size_t)b * 16384 * 256;
#pragma unroll
    for (int rep = 0; rep < 16; ++rep) {
        int cl = rep * 4 + (tid >> 6);
        int pl = tid & 63;
        float v = inb[(size_t)(ci0 + cl) * 16384 + px0 + pl];
        if (doRelu) v = fmaxf(v, 0.f);
        s[pl * 66 + cl] = (short)f2bf(v);
    }
    __syncthreads();
#pragma unroll
    for (int rep = 0; rep < 2; ++rep) {
        int c = rep * 256 + tid;
        int pl = c >> 3;
        int cl = (c & 7) * 8;
        *(short8*)&ob[(size_t)(px0 + pl) * 256 + ci0 + cl] = *(const short8*)&s[pl * 66 + cl];
    }
}

// ---------------- MFMA implicit-GEMM 3x3 conv, NHWC bf16 in/out (r15-validated) ----------------
// EPI: 0 = bias, 1 = bias+relu, 2 = (bias+v)*x, 3 = bias+relu + fused 1x1 -> out4
template<int TW, int OUTC, int EPI>
__global__ __launch_bounds__(512, 2)
void conv_mfma_kernel(const ushort_t* __restrict__ in, const ushort_t* __restrict__ wpk,
                      const float* __restrict__ bias, int coutReal,
                      const ushort_t* __restrict__ xin, ushort_t* __restrict__ outp,
                      const ushort_t* __restrict__ zp,
                      const float* __restrict__ w4g, const float* __restrict__ b4g,
                      float* __restrict__ out4)
{
    constexpr int NF = OUTC / 16;
    constexpr int NN = (NF < 4) ? NF : 4;
    constexpr int HWD = TW + 2;
    constexpr int HPX = 6 * HWD;
    constexpr int ROUNDS = (HPX * 4 + 511) / 512;
    constexpr int MW  = TW / 16;
    constexpr int MPW = TW / 8;
    constexpr int PITCH = OUTC + 4;
    union SM { short a[2][ROUNDS * 512 * 8]; float e[TW * PITCH]; };
    __shared__ __align__(16) SM sm;

    const int tid  = threadIdx.x;
    const int lane = tid & 63;
    const int wv   = tid >> 6;
    const int hi   = lane >> 4;
    const int lo   = lane & 15;
    const int pxg  = wv & 1;
    const int wn   = wv >> 1;
    const int wnu  = __builtin_amdgcn_readfirstlane(wn);
    const int x0 = blockIdx.x * TW;
    const int y0 = blockIdx.y * 4;
    const int b  = blockIdx.z;
    const ushort_t* inb = in + (size_t)b * 16384 * 256;

    const ushort_t* sptr[ROUNDS];
    int sstep[ROUNDS];
#pragma unroll
    for (int r = 0; r < ROUNDS; ++r) {
        int g = r * 512 + tid;
        int px = g >> 2, slot = g & 3;
        int hy = px / HWD, hx = px - hy * HWD;
        int gy = y0 - 1 + hy, gx = x0 - 1 + hx;
        bool ok = (px < HPX) && ((unsigned)gy < 128u) && ((unsigned)gx < 128u);
        int kk = (px ^ (px >> 2)) & 3;
        sptr[r] = ok ? (inb + (size_t)((gy << 7) + gx) * 256 + ((slot ^ kk) << 3))
                     : (zp + (slot << 3));
        sstep[r] = ok ? 32 : 0;
    }

    int pxh_base[MPW];
#pragma unroll
    for (int m = 0; m < MPW; ++m)
        pxh_base[m] = (2 * pxg + m / MW) * HWD + (m % MW) * 16 + lo;

    f32x4 acc[MPW][NN];
#pragma unroll
    for (int m = 0; m < MPW; ++m)
#pragma unroll
        for (int n = 0; n < NN; ++n) acc[m][n] = (f32x4){0.f, 0.f, 0.f, 0.f};

#pragma unroll
    for (int r = 0; r < ROUNDS; ++r)
        gload_lds16(sptr[r], &sm.a[0][(r * 512 + wv * 64) * 8]);
    __syncthreads();

    for (int cc = 0; cc < 8; ++cc) {
        const int buf = cc & 1;
        if (cc < 7) {
#pragma unroll
            for (int r = 0; r < ROUNDS; ++r)
                gload_lds16(sptr[r] + (size_t)(cc + 1) * sstep[r],
                            &sm.a[buf ^ 1][(r * 512 + wv * 64) * 8]);
        }
        if (NF >= 4 || wnu == 0) {
#pragma unroll
            for (int t = 0; t < 9; ++t) {
                const int ky = t / 3, kx = t % 3;
                short8 bf[NN];
#pragma unroll
                for (int n = 0; n < NN; ++n)
                    bf[n] = *(const short8*)&wpk[((size_t)((t * 8 + cc) * NF + wnu * NN + n) * 64 + lane) * 8];
                short8 af[MPW];
#pragma unroll
                for (int m = 0; m < MPW; ++m) {
                    int ph = pxh_base[m] + ky * HWD + kx;
                    int off = ph * 32 + ((hi ^ ((ph ^ (ph >> 2)) & 3)) << 3);
                    af[m] = *(const short8*)&sm.a[buf][off];
                }
#pragma unroll
                for (int m = 0; m < MPW; ++m)
#pragma unroll
                    for (int n = 0; n < NN; ++n)
                        acc[m][n] = __builtin_amdgcn_mfma_f32_16x16x32_bf16(af[m], bf[n], acc[m][n], 0, 0, 0);
            }
        }
        __syncthreads();
    }

    float br[NN];
#pragma unroll
    for (int n = 0; n < NN; ++n) {
        int oc = wn * (16 * NN) + n * 16 + lo;
        br[n] = (oc < coutReal) ? bias[oc] : 0.f;
    }
    const size_t obase = ((size_t)b * 16384 + (size_t)y0 * 128 + x0) * OUTC;
#pragma unroll
    for (int p = 0; p < 4; ++p) {
        if (pxg == (p >> 1) && (NF >= 4 || wnu == 0)) {
#pragma unroll
            for (int mm = 0; mm < MW; ++mm) {
                int m = (p & 1) * MW + mm;
#pragma unroll
                for (int n = 0; n < NN; ++n)
#pragma unroll
                    for (int r = 0; r < 4; ++r) {
                        int col = mm * 16 + hi * 4 + r;
                        float v = acc[m][n][r] + br[n];
                        if (EPI == 1 || EPI == 3) v = fmaxf(v, 0.f);
                        sm.e[col * PITCH + wn * (16 * NN) + n * 16 + lo] = v;
                    }
            }
        }
        __syncthreads();
        if constexpr (EPI == 3) {
            int col = tid >> 5;
            int ch  = tid & 31;
            f32x4 v0 = *(const f32x4*)&sm.e[col * PITCH + ch * 8];
            f32x4 v1 = *(const f32x4*)&sm.e[col * PITCH + ch * 8 + 4];
            float4 wa0 = *(const float4*)&w4g[ch * 8];
            float4 wa1 = *(const float4*)&w4g[ch * 8 + 4];
            float4 wb0 = *(const float4*)&w4g[256 + ch * 8];
            float4 wb1 = *(const float4*)&w4g[256 + ch * 8 + 4];
            float a0 = v0[0] * wa0.x + v0[1] * wa0.y + v0[2] * wa0.z + v0[3] * wa0.w
                     + v1[0] * wa1.x + v1[1] * wa1.y + v1[2] * wa1.z + v1[3] * wa1.w;
            float a1 = v0[0] * wb0.x + v0[1] * wb0.y + v0[2] * wb0.z + v0[3] * wb0.w
                     + v1[0] * wb1.x + v1[1] * wb1.y + v1[2] * wb1.z + v1[3] * wb1.w;
#pragma unroll
            for (int s = 16; s >= 1; s >>= 1) {
                a0 += __shfl_xor(a0, s);
                a1 += __shfl_xor(a1, s);
            }
            if (ch == 0) {
                size_t o = (size_t)b * 2 * 16384 + (size_t)(y0 + p) * 128 + x0 + col;
                out4[o]         = a0 + b4g[0];
                out4[o + 16384] = a1 + b4g[1];
            }
        } else {
            constexpr int CHUNKS = TW * OUTC / 8;
            for (int c = tid; c < CHUNKS; c += 512) {
                int col = c / (OUTC / 8);
                int ch = c % (OUTC / 8);
                f32x4 v0 = *(const f32x4*)&sm.e[col * PITCH + ch * 8];
                f32x4 v1 = *(const f32x4*)&sm.e[col * PITCH + ch * 8 + 4];
                size_t gidx = obase + ((size_t)p * 128 + col) * OUTC + ch * 8;
                if (EPI == 2) {
                    uint4v xu = *(const uint4v*)&xin[gidx];
#pragma unroll
                    for (int j = 0; j < 4; ++j) {
                        float xa = bf2f((ushort_t)(xu[j] & 0xffffu));
                        float xb = __builtin_bit_cast(float, xu[j] & 0xffff0000u);
                        if (j < 2) { v0[2 * j] *= xa; v0[2 * j + 1] *= xb; }
                        else       { v1[2 * (j - 2)] *= xa; v1[2 * (j - 2) + 1] *= xb; }
                    }
                }
                short8 s;
#pragma unroll
                for (int j = 0; j < 4; ++j) s[j] = (short)f2bf(v0[j]);
#pragma unroll
                for (int j = 0; j < 4; ++j) s[4 + j] = (short)f2bf(v1[j]);
                *(short8*)&outp[gidx] = s;
            }
        }
        __syncthreads();
    }
}

// ---------------- DCN v2: 16x4 px x 256 oc, 512 blocks x 512 thr (8 waves), 16 waves/CU ----------------
// Each thread: 1 pixel x 1 ci-chunk (4 gathers/iter). Each wave: 2 n-frags x 2 k-chunks MFMA.
__device__ inline void corner8(uint4v u, float w, float* sv) {
#pragma unroll
    for (int j = 0; j < 4; ++j) {
        unsigned a = u[j];
        sv[2 * j]     = fmaf(w, __builtin_bit_cast(float, a << 16), sv[2 * j]);
        sv[2 * j + 1] = fmaf(w, __builtin_bit_cast(float, a & 0xffff0000u), sv[2 * j + 1]);
    }
}

__global__ __launch_bounds__(512, 4)
void dcn_mfma_kernel(const ushort_t* __restrict__ ft, const ushort_t* __restrict__ omt,
                     const ushort_t* __restrict__ wpk, const float* __restrict__ bias,
                     ushort_t* __restrict__ outp)
{
    union SM { short a[2][2][2048]; float e[16 * 264]; };
    __shared__ __align__(16) SM sm;

    const int tid  = threadIdx.x;
    const int lane = tid & 63;
    const int wv   = tid >> 6;          // 0..7: n-frag pair owner
    const int hi   = lane >> 4;
    const int lo   = lane & 15;
    const int bid  = blockIdx.x;
    const int tile = (bid & 7) * 64 + (bid >> 3);
    const int b    = tile >> 8;
    const int rem  = tile & 255;
    const int y0   = (rem >> 3) * 4;
    const int x0   = (rem & 7) * 16;
    const ushort_t* fb = ft + (size_t)b * 16384 * 256;

    // sampling map: 4 consecutive lanes = same pixel+chunk, 4 ci-slices
    const int q   = tid & 3;            // ci slice (8 of 32)
    const int hc  = (tid >> 2) & 1;     // ci-chunk half (0/1 of the 64-ci pair)
    const int pxl = tid >> 3;           // 0..63

    float mw[9][4];
    unsigned mc[9];
    {
        const int py = y0 + (pxl >> 4), pxx = x0 + (pxl & 15);
        const ushort_t* omp = omt + ((size_t)b * 16384 + py * 128 + pxx) * 32;
        uint4v ow[4];
#pragma unroll
        for (int j = 0; j < 4; ++j) ow[j] = *(const uint4v*)(omp + j * 8);
        unsigned wbuf[14];
#pragma unroll
        for (int j = 0; j < 4; ++j)
#pragma unroll
            for (int e = 0; e < 4; ++e)
                if (j * 4 + e < 14) wbuf[j * 4 + e] = ow[j][e];
#pragma unroll
        for (int t = 0; t < 9; ++t) {
            float dy = bf2f((ushort_t)(wbuf[t] & 0xffffu));
            float dx = bf2f((ushort_t)(wbuf[t] >> 16));
            unsigned mw_ = wbuf[(18 + t) >> 1];
            float mr = ((18 + t) & 1) ? bf2f((ushort_t)(mw_ >> 16)) : bf2f((ushort_t)(mw_ & 0xffffu));
            float mk = 1.f / (1.f + expf(-mr));
            float ys = (float)(py - 1 + t / 3) + dy;
            float xs = (float)(pxx - 1 + t % 3) + dx;
            float y0f = floorf(ys), x0f = floorf(xs);
            float wy1 = ys - y0f, wx1 = xs - x0f;
            float wy0 = 1.f - wy1, wx0 = 1.f - wx1;
            int yi = (int)y0f, xi = (int)x0f;
            bool vy0 = (yi >= 0) && (yi < 128), vy1 = (yi + 1 >= 0) && (yi + 1 < 128);
            bool vx0 = (xi >= 0) && (xi < 128), vx1 = (xi + 1 >= 0) && (xi + 1 < 128);
            mw[t][0] = (vy0 && vx0) ? wy0 * wx0 * mk : 0.f;
            mw[t][1] = (vy0 && vx1) ? wy0 * wx1 * mk : 0.f;
            mw[t][2] = (vy1 && vx0) ? wy1 * wx0 * mk : 0.f;
            mw[t][3] = (vy1 && vx1) ? wy1 * wx1 * mk : 0.f;
            int y0c = min(max(yi, 0), 127), y1c = min(max(yi + 1, 0), 127);
            int x0c = min(max(xi, 0), 127), x1c = min(max(xi + 1, 0), 127);
            mc[t] = (unsigned)y0c | ((unsigned)y1c << 8) | ((unsigned)x0c << 16) | ((unsigned)x1c << 24);
        }
    }

    const int w_off = pxl * 32 + ((q ^ ((pxl ^ (pxl >> 2)) & 3)) << 3);
    int a_off[4];
#pragma unroll
    for (int m = 0; m < 4; ++m) {
        int p_ = m * 16 + lo;
        a_off[m] = p_ * 32 + ((hi ^ ((p_ ^ (p_ >> 2)) & 3)) << 3);
    }

    f32x4 acc[4][2];
#pragma unroll
    for (int m = 0; m < 4; ++m)
#pragma unroll
        for (int n = 0; n < 2; ++n) acc[m][n] = (f32x4){0.f, 0.f, 0.f, 0.f};

    uint4v na, nb, nc, nd;

    // ---- prologue: sample (cch=0, own chunk, t=0) into buf 0 ----
    {
        unsigned c = mc[0];
        int yy0 = c & 255, yy1 = (c >> 8) & 255, xx0 = (c >> 16) & 255, xx1 = c >> 24;
        const ushort_t* pc = fb + hc * 32 + q * 8;
        na = *(const uint4v*)(pc + (size_t)((yy0 << 7) + xx0) * 256);
        nb = *(const uint4v*)(pc + (size_t)((yy0 << 7) + xx1) * 256);
        nc = *(const uint4v*)(pc + (size_t)((yy1 << 7) + xx0) * 256);
        nd = *(const uint4v*)(pc + (size_t)((yy1 << 7) + xx1) * 256);
        float sv[8] = {0.f, 0.f, 0.f, 0.f, 0.f, 0.f, 0.f, 0.f};
        corner8(na, mw[0][0], sv); corner8(nb, mw[0][1], sv);
        corner8(nc, mw[0][2], sv); corner8(nd, mw[0][3], sv);
        unsigned pk[4];
#pragma unroll
        for (int j = 0; j < 4; ++j)
            asm("v_cvt_pk_bf16_f32 %0, %1, %2" : "=v"(pk[j]) : "v"(sv[2 * j]), "v"(sv[2 * j + 1]));
        *(uint4v*)&sm.a[0][hc][w_off] = (uint4v){pk[0], pk[1], pk[2], pk[3]};
    }
    __syncthreads();

    // ---- main loop: 36 iters (cch 0..3 x t 0..8), K=64 per iter, 1 barrier/iter ----
    for (int cch = 0; cch < 4; ++cch) {
#pragma unroll
        for (int t = 0; t < 9; ++t) {
            const int cur = (cch + t) & 1;
            const bool last = (cch == 3) && (t == 8);
            const int tn   = (t == 8) ? 0 : t + 1;
            const int cchn = (t == 8) ? cch + 1 : cch;
            // 1. issue next iteration's gathers (own chunk only: 4 loads)
            if (!last) {
                unsigned c = mc[tn];
                int yy0 = c & 255, yy1 = (c >> 8) & 255, xx0 = (c >> 16) & 255, xx1 = c >> 24;
                const ushort_t* pc = fb + (2 * cchn + hc) * 32 + q * 8;
                na = *(const uint4v*)(pc + (size_t)((yy0 << 7) + xx0) * 256);
                nb = *(const uint4v*)(pc + (size_t)((yy0 << 7) + xx1) * 256);
                nc = *(const uint4v*)(pc + (size_t)((yy1 << 7) + xx0) * 256);
                nd = *(const uint4v*)(pc + (size_t)((yy1 << 7) + xx1) * 256);
            }
            // 2. B fragments: wave-unique n-frag pair, both k-chunks
            short8 bfr0[2], bfr1[2];
            {
                const ushort_t* bs0 = wpk + ((size_t)((t * 8 + 2 * cch) * 16 + wv * 2) * 64 + lane) * 8;
#pragma unroll
                for (int n = 0; n < 2; ++n)
                    bfr0[n] = *(const short8*)(bs0 + (size_t)n * 512);
                const ushort_t* bs1 = bs0 + 16 * 512;
#pragma unroll
                for (int n = 0; n < 2; ++n)
                    bfr1[n] = *(const short8*)(bs1 + (size_t)n * 512);
            }
            // 3. MFMA: 4 m-frags x 2 n-frags x 2 k-chunks
#pragma unroll
            for (int m = 0; m < 4; ++m) {
                short8 af0 = *(const short8*)&sm.a[cur][0][a_off[m]];
                short8 af1 = *(const short8*)&sm.a[cur][1][a_off[m]];
#pragma unroll
                for (int n = 0; n < 2; ++n)
                    acc[m][n] = __builtin_amdgcn_mfma_f32_16x16x32_bf16(af0, bfr0[n], acc[m][n], 0, 0, 0);
#pragma unroll
                for (int n = 0; n < 2; ++n)
                    acc[m][n] = __builtin_amdgcn_mfma_f32_16x16x32_bf16(af1, bfr1[n], acc[m][n], 0, 0, 0);
            }
            // 4. combine next gathers, write other LDS buffer
            if (!last) {
                float sv[8] = {0.f, 0.f, 0.f, 0.f, 0.f, 0.f, 0.f, 0.f};
                corner8(na, mw[tn][0], sv); corner8(nb, mw[tn][1], sv);
                corner8(nc, mw[tn][2], sv); corner8(nd, mw[tn][3], sv);
                unsigned pk[4];
#pragma unroll
                for (int j = 0; j < 4; ++j)
                    asm("v_cvt_pk_bf16_f32 %0, %1, %2" : "=v"(pk[j]) : "v"(sv[2 * j]), "v"(sv[2 * j + 1]));
                *(uint4v*)&sm.a[cur ^ 1][hc][w_off] = (uint4v){pk[0], pk[1], pk[2], pk[3]};
            }
            __syncthreads();
        }
    }

    // ---- epilogue: bias + relu -> NHWC bf16; wave wv owns oc 32*wv..32*wv+31 ----
    float br[2];
#pragma unroll
    for (int n = 0; n < 2; ++n) br[n] = bias[wv * 32 + n * 16 + lo];
#pragma unroll
    for (int p = 0; p < 4; ++p) {
#pragma unroll
        for (int n = 0; n < 2; ++n)
#pragma unroll
            for (int r = 0; r < 4; ++r)
                sm.e[(hi * 4 + r) * 264 + wv * 32 + n * 16 + lo] = fmaxf(acc[p][n][r] + br[n], 0.f);
        __syncthreads();
        {
            int pl = tid >> 5, ch = tid & 31;
            f32x4 v0 = *(const f32x4*)&sm.e[pl * 264 + ch * 8];
            f32x4 v1 = *(const f32x4*)&sm.e[pl * 264 + ch * 8 + 4];
            short8 s;
#pragma unroll
            for (int jj = 0; jj < 4; ++jj) s[jj] = (short)f2bf(v0[jj]);
#pragma unroll
            for (int jj = 0; jj < 4; ++jj) s[4 + jj] = (short)f2bf(v1[jj]);
            *(short8*)&outp[((size_t)b * 16384 + (size_t)(y0 + p) * 128 + x0 + pl) * 256 + ch * 8] = s;
        }
        __syncthreads();
    }
}

// ---------------- host launch ----------------
extern "C" void kernel_launch(void* const* d_in, const int* in_sizes, int n_in,
                              void* d_out, int out_size, void* d_ws, size_t ws_size,
                              hipStream_t stream) {
    const float* x     = (const float*)d_in[0];
    const float* votes = (const float*)d_in[1];
    const float* w1    = (const float*)d_in[2];
    const float* b1    = (const float*)d_in[3];
    const float* w_off = (const float*)d_in[4];
    const float* b_off = (const float*)d_in[5];
    const float* w_dcn = (const float*)d_in[6];
    const float* b_dcn = (const float*)d_in[7];
    const float* w2    = (const float*)d_in[8];
    const float* b2    = (const float*)d_in[9];
    const float* w3    = (const float*)d_in[10];
    const float* b3    = (const float*)d_in[11];
    const float* w4    = (const float*)d_in[12];
    const float* b4    = (const float*)d_in[13];
    float* outp = (float*)d_out;

    const int B = 2;
    const size_t featN = (size_t)B * 16384 * 256;

    ushort_t* ws   = (ushort_t*)d_ws;
    ushort_t* t1   = ws;
    ushort_t* t2   = t1 + featN;
    ushort_t* aN   = t2 + featN;
    ushort_t* xN   = aN + featN;
    ushort_t* om   = xN + featN;
    ushort_t* wpk1 = om + (size_t)B * 16384 * 32;
    ushort_t* wpkO = wpk1 + 589824;
    ushort_t* wpkD = wpkO + 73728;
    ushort_t* wpk2 = wpkD + 589824;
    ushort_t* wpk3 = wpk2 + 589824;
    ushort_t* zp   = wpk3 + 589824;

    // all prep (weight packs + zero page + NHWC transposes): ONE launch
    prep_all_kernel<<<1189 + 4096, 256, 0, stream>>>(w1, wpk1, w_off, wpkO, w_dcn, wpkD,
                                                     w2, wpk2, w3, wpk3, zp, votes, x, aN, xN);

    dim3 cg16(8, 32, B);
    // conv1: t1 = relu(conv(relu(votes), w1, b1))
    conv_mfma_kernel<16, 256, 1><<<cg16, 512, 0, stream>>>(aN, wpk1, b1, 256, nullptr, t1, zp, nullptr, nullptr, nullptr);
    // conv_off: om = conv(t1, w_off, b_off)
    conv_mfma_kernel<16, 32, 0><<<cg16, 512, 0, stream>>>(t1, wpkO, b_off, 27, nullptr, om, zp, nullptr, nullptr, nullptr);
    // dcn: t2 = relu(dcn(t1, om, w_dcn, b_dcn))  — 512 blocks x 512 threads (16 waves/CU)
    dcn_mfma_kernel<<<512, 512, 0, stream>>>(t1, om, wpkD, b_dcn, t2);
    // conv2 + fuse: g = (conv(t2, w2) + b2) * x
    conv_mfma_kernel<16, 256, 2><<<cg16, 512, 0, stream>>>(t2, wpk2, b2, 256, xN, aN, zp, nullptr, nullptr, nullptr);
    // conv3 + fused 1x1: out = conv1x1(relu(conv(g, w3, b3)), w4, b4)
    conv_mfma_kernel<16, 256, 3><<<cg16, 512, 0, stream>>>(aN, wpk3, b3, 256, nullptr, nullptr, zp, w4, b4, outp);
}

// Round 19
// 260.743 us; speedup vs baseline: 1.0559x; 1.0559x over previous
//
#include <hip/hip_runtime.h>
#include <math.h>

typedef short short8 __attribute__((ext_vector_type(8)));
typedef float f32x4 __attribute__((ext_vector_type(4)));
typedef unsigned int uint4v __attribute__((ext_vector_type(4)));
typedef unsigned short ushort_t;

__device__ inline ushort_t f2bf(float f) {
    unsigned u = __builtin_bit_cast(unsigned, f);
    u = (u + 0x7fffu + ((u >> 16) & 1u)) >> 16;   // RNE
    return (ushort_t)u;
}
__device__ inline float bf2f(ushort_t u) {
    return __builtin_bit_cast(float, (unsigned)u << 16);
}
__device__ inline void gload_lds16(const ushort_t* g, short* l) {
    __builtin_amdgcn_global_load_lds((const __attribute__((address_space(1))) unsigned int*)g,
                                     (__attribute__((address_space(3))) unsigned int*)l, 16, 0, 0);
}

// ---------------- prep: all weight packs + zero page + both NHWC transposes, ONE launch ----------------
__device__ inline void wpack_body(const float* __restrict__ w, ushort_t* __restrict__ wpk,
                                  int COUT, int NF, int bidLocal, int tid) {
    int T = bidLocal * 256 + tid;
    int lane = T & 63;
    int rest = T >> 6;
    int n = rest % NF;
    int kstep = rest / NF;          // 0..71
    int t = kstep >> 3, cc = kstep & 7;
    int oc = n * 16 + (lane & 15);
    int kk = (lane >> 4) * 8;
    short8 sv;
#pragma unroll
    for (int j = 0; j < 8; ++j) {
        int ci = cc * 32 + kk + j;
        float val = (oc < COUT) ? w[((size_t)oc * 256 + ci) * 9 + t] : 0.f;
        sv[j] = (short)f2bf(val);
    }
    *(short8*)&wpk[(size_t)T * 8] = sv;
}

__global__ __launch_bounds__(256)
void prep_all_kernel(const float* w1, ushort_t* wpk1,
                     const float* w_off, ushort_t* wpkO,
                     const float* w_dcn, ushort_t* wpkD,
                     const float* w2, ushort_t* wpk2,
                     const float* w3, ushort_t* wpk3,
                     ushort_t* zp,
                     const float* __restrict__ votes, const float* __restrict__ x,
                     ushort_t* __restrict__ aN, ushort_t* __restrict__ xN) {
    __shared__ short s[64 * 66];
    int bid = blockIdx.x, tid = threadIdx.x;
    if (bid < 288)       { wpack_body(w1,    wpk1, 256, 16, bid,        tid); return; }
    else if (bid < 324)  { wpack_body(w_off, wpkO, 27,  2,  bid - 288,  tid); return; }
    else if (bid < 612)  { wpack_body(w_dcn, wpkD, 256, 16, bid - 324,  tid); return; }
    else if (bid < 900)  { wpack_body(w2,    wpk2, 256, 16, bid - 612,  tid); return; }
    else if (bid < 1188) { wpack_body(w3,    wpk3, 256, 16, bid - 900,  tid); return; }
    else if (bid == 1188) { zp[tid] = 0; return; }
    // nhwc transpose blocks
    int nb = bid - 1189;                  // 0..4095
    const int px0 = (nb & 255) * 64;
    const int ci0 = ((nb >> 8) & 3) * 64;
    const int z   = nb >> 10;             // 0,1 = votes(relu); 2,3 = x
    const int b   = z & 1;
    const bool doRelu = (z < 2);
    const float* inb = (doRelu ? votes : x) + (size_t)b * 256 * 16384;
    ushort_t* ob = (doRelu ? aN : xN) + (size_t)b * 16384 * 256;
#pragma unroll
    for (int rep = 0; rep < 16; ++rep) {
        int cl = rep * 4 + (tid >> 6);
        int pl = tid & 63;
        float v = inb[(size_t)(ci0 + cl) * 16384 + px0 + pl];
        if (doRelu) v = fmaxf(v, 0.f);
        s[pl * 66 + cl] = (short)f2bf(v);
    }
    __syncthreads();
#pragma unroll
    for (int rep = 0; rep < 2; ++rep) {
        int c = rep * 256 + tid;
        int pl = c >> 3;
        int cl = (c & 7) * 8;
        *(short8*)&ob[(size_t)(px0 + pl) * 256 + ci0 + cl] = *(const short8*)&s[pl * 66 + cl];
    }
}

// ---------------- MFMA implicit-GEMM 3x3 conv, NHWC bf16 in/out (r15-validated) ----------------
// EPI: 0 = bias, 1 = bias+relu, 2 = (bias+v)*x, 3 = bias+relu + fused 1x1 -> out4
template<int TW, int OUTC, int EPI>
__global__ __launch_bounds__(512, 2)
void conv_mfma_kernel(const ushort_t* __restrict__ in, const ushort_t* __restrict__ wpk,
                      const float* __restrict__ bias, int coutReal,
                      const ushort_t* __restrict__ xin, ushort_t* __restrict__ outp,
                      const ushort_t* __restrict__ zp,
                      const float* __restrict__ w4g, const float* __restrict__ b4g,
                      float* __restrict__ out4)
{
    constexpr int NF = OUTC / 16;
    constexpr int NN = (NF < 4) ? NF : 4;
    constexpr int HWD = TW + 2;
    constexpr int HPX = 6 * HWD;
    constexpr int ROUNDS = (HPX * 4 + 511) / 512;
    constexpr int MW  = TW / 16;
    constexpr int MPW = TW / 8;
    constexpr int PITCH = OUTC + 4;
    union SM { short a[2][ROUNDS * 512 * 8]; float e[TW * PITCH]; };
    __shared__ __align__(16) SM sm;

    const int tid  = threadIdx.x;
    const int lane = tid & 63;
    const int wv   = tid >> 6;
    const int hi   = lane >> 4;
    const int lo   = lane & 15;
    const int pxg  = wv & 1;
    const int wn   = wv >> 1;
    const int wnu  = __builtin_amdgcn_readfirstlane(wn);
    const int x0 = blockIdx.x * TW;
    const int y0 = blockIdx.y * 4;
    const int b  = blockIdx.z;
    const ushort_t* inb = in + (size_t)b * 16384 * 256;

    const ushort_t* sptr[ROUNDS];
    int sstep[ROUNDS];
#pragma unroll
    for (int r = 0; r < ROUNDS; ++r) {
        int g = r * 512 + tid;
        int px = g >> 2, slot = g & 3;
        int hy = px / HWD, hx = px - hy * HWD;
        int gy = y0 - 1 + hy, gx = x0 - 1 + hx;
        bool ok = (px < HPX) && ((unsigned)gy < 128u) && ((unsigned)gx < 128u);
        int kk = (px ^ (px >> 2)) & 3;
        sptr[r] = ok ? (inb + (size_t)((gy << 7) + gx) * 256 + ((slot ^ kk) << 3))
                     : (zp + (slot << 3));
        sstep[r] = ok ? 32 : 0;
    }

    int pxh_base[MPW];
#pragma unroll
    for (int m = 0; m < MPW; ++m)
        pxh_base[m] = (2 * pxg + m / MW) * HWD + (m % MW) * 16 + lo;

    f32x4 acc[MPW][NN];
#pragma unroll
    for (int m = 0; m < MPW; ++m)
#pragma unroll
        for (int n = 0; n < NN; ++n) acc[m][n] = (f32x4){0.f, 0.f, 0.f, 0.f};

#pragma unroll
    for (int r = 0; r < ROUNDS; ++r)
        gload_lds16(sptr[r], &sm.a[0][(r * 512 + wv * 64) * 8]);
    __syncthreads();

    for (int cc = 0; cc < 8; ++cc) {
        const int buf = cc & 1;
        if (cc < 7) {
#pragma unroll
            for (int r = 0; r < ROUNDS; ++r)
                gload_lds16(sptr[r] + (size_t)(cc + 1) * sstep[r],
                            &sm.a[buf ^ 1][(r * 512 + wv * 64) * 8]);
        }
        if (NF >= 4 || wnu == 0) {
#pragma unroll
            for (int t = 0; t < 9; ++t) {
                const int ky = t / 3, kx = t % 3;
                short8 bf[NN];
#pragma unroll
                for (int n = 0; n < NN; ++n)
                    bf[n] = *(const short8*)&wpk[((size_t)((t * 8 + cc) * NF + wnu * NN + n) * 64 + lane) * 8];
                short8 af[MPW];
#pragma unroll
                for (int m = 0; m < MPW; ++m) {
                    int ph = pxh_base[m] + ky * HWD + kx;
                    int off = ph * 32 + ((hi ^ ((ph ^ (ph >> 2)) & 3)) << 3);
                    af[m] = *(const short8*)&sm.a[buf][off];
                }
#pragma unroll
                for (int m = 0; m < MPW; ++m)
#pragma unroll
                    for (int n = 0; n < NN; ++n)
                        acc[m][n] = __builtin_amdgcn_mfma_f32_16x16x32_bf16(af[m], bf[n], acc[m][n], 0, 0, 0);
            }
        }
        __syncthreads();
    }

    float br[NN];
#pragma unroll
    for (int n = 0; n < NN; ++n) {
        int oc = wn * (16 * NN) + n * 16 + lo;
        br[n] = (oc < coutReal) ? bias[oc] : 0.f;
    }
    const size_t obase = ((size_t)b * 16384 + (size_t)y0 * 128 + x0) * OUTC;
#pragma unroll
    for (int p = 0; p < 4; ++p) {
        if (pxg == (p >> 1) && (NF >= 4 || wnu == 0)) {
#pragma unroll
            for (int mm = 0; mm < MW; ++mm) {
                int m = (p & 1) * MW + mm;
#pragma unroll
                for (int n = 0; n < NN; ++n)
#pragma unroll
                    for (int r = 0; r < 4; ++r) {
                        int col = mm * 16 + hi * 4 + r;
                        float v = acc[m][n][r] + br[n];
                        if (EPI == 1 || EPI == 3) v = fmaxf(v, 0.f);
                        sm.e[col * PITCH + wn * (16 * NN) + n * 16 + lo] = v;
                    }
            }
        }
        __syncthreads();
        if constexpr (EPI == 3) {
            int col = tid >> 5;
            int ch  = tid & 31;
            f32x4 v0 = *(const f32x4*)&sm.e[col * PITCH + ch * 8];
            f32x4 v1 = *(const f32x4*)&sm.e[col * PITCH + ch * 8 + 4];
            float4 wa0 = *(const float4*)&w4g[ch * 8];
            float4 wa1 = *(const float4*)&w4g[ch * 8 + 4];
            float4 wb0 = *(const float4*)&w4g[256 + ch * 8];
            float4 wb1 = *(const float4*)&w4g[256 + ch * 8 + 4];
            float a0 = v0[0] * wa0.x + v0[1] * wa0.y + v0[2] * wa0.z + v0[3] * wa0.w
                     + v1[0] * wa1.x + v1[1] * wa1.y + v1[2] * wa1.z + v1[3] * wa1.w;
            float a1 = v0[0] * wb0.x + v0[1] * wb0.y + v0[2] * wb0.z + v0[3] * wb0.w
                     + v1[0] * wb1.x + v1[1] * wb1.y + v1[2] * wb1.z + v1[3] * wb1.w;
#pragma unroll
            for (int s = 16; s >= 1; s >>= 1) {
                a0 += __shfl_xor(a0, s);
                a1 += __shfl_xor(a1, s);
            }
            if (ch == 0) {
                size_t o = (size_t)b * 2 * 16384 + (size_t)(y0 + p) * 128 + x0 + col;
                out4[o]         = a0 + b4g[0];
                out4[o + 16384] = a1 + b4g[1];
            }
        } else {
            constexpr int CHUNKS = TW * OUTC / 8;
            for (int c = tid; c < CHUNKS; c += 512) {
                int col = c / (OUTC / 8);
                int ch = c % (OUTC / 8);
                f32x4 v0 = *(const f32x4*)&sm.e[col * PITCH + ch * 8];
                f32x4 v1 = *(const f32x4*)&sm.e[col * PITCH + ch * 8 + 4];
                size_t gidx = obase + ((size_t)p * 128 + col) * OUTC + ch * 8;
                if (EPI == 2) {
                    uint4v xu = *(const uint4v*)&xin[gidx];
#pragma unroll
                    for (int j = 0; j < 4; ++j) {
                        float xa = bf2f((ushort_t)(xu[j] & 0xffffu));
                        float xb = __builtin_bit_cast(float, xu[j] & 0xffff0000u);
                        if (j < 2) { v0[2 * j] *= xa; v0[2 * j + 1] *= xb; }
                        else       { v1[2 * (j - 2)] *= xa; v1[2 * (j - 2) + 1] *= xb; }
                    }
                }
                short8 s;
#pragma unroll
                for (int j = 0; j < 4; ++j) s[j] = (short)f2bf(v0[j]);
#pragma unroll
                for (int j = 0; j < 4; ++j) s[4 + j] = (short)f2bf(v1[j]);
                *(short8*)&outp[gidx] = s;
            }
        }
        __syncthreads();
    }
}

// ---------------- DCN v2: 16x4 px x 256 oc, 512 blocks x 512 thr, 16 waves/CU (128-VGPR cap) ----------------
// Each thread: 1 pixel x 1 ci-chunk (4 gathers/iter). Each wave: 2 n-frags x 2 k-chunks MFMA.
__device__ inline void corner8(uint4v u, float w, float* sv) {
#pragma unroll
    for (int j = 0; j < 4; ++j) {
        unsigned a = u[j];
        sv[2 * j]     = fmaf(w, __builtin_bit_cast(float, a << 16), sv[2 * j]);
        sv[2 * j + 1] = fmaf(w, __builtin_bit_cast(float, a & 0xffff0000u), sv[2 * j + 1]);
    }
}

__global__ __launch_bounds__(512, 2)
void dcn_mfma_kernel(const ushort_t* __restrict__ ft, const ushort_t* __restrict__ omt,
                     const ushort_t* __restrict__ wpk, const float* __restrict__ bias,
                     ushort_t* __restrict__ outp)
{
    union SM { short a[2][2][2048]; float e[16 * 264]; };
    __shared__ __align__(16) SM sm;

    const int tid  = threadIdx.x;
    const int lane = tid & 63;
    const int wv   = tid >> 6;          // 0..7: n-frag pair owner
    const int hi   = lane >> 4;
    const int lo   = lane & 15;
    const int bid  = blockIdx.x;
    const int tile = (bid & 7) * 64 + (bid >> 3);
    const int b    = tile >> 8;
    const int rem  = tile & 255;
    const int y0   = (rem >> 3) * 4;
    const int x0   = (rem & 7) * 16;
    const ushort_t* fb = ft + (size_t)b * 16384 * 256;

    // sampling map: 4 consecutive lanes = same pixel+chunk, 4 ci-slices
    const int q   = tid & 3;            // ci slice (8 of 32)
    const int hc  = (tid >> 2) & 1;     // ci-chunk half (0/1 of the 64-ci pair)
    const int pxl = tid >> 3;           // 0..63

    float mw[9][4];
    unsigned mc[9];
    {
        const int py = y0 + (pxl >> 4), pxx = x0 + (pxl & 15);
        const ushort_t* omp = omt + ((size_t)b * 16384 + py * 128 + pxx) * 32;
        uint4v ow[4];
#pragma unroll
        for (int j = 0; j < 4; ++j) ow[j] = *(const uint4v*)(omp + j * 8);
        unsigned wbuf[14];
#pragma unroll
        for (int j = 0; j < 4; ++j)
#pragma unroll
            for (int e = 0; e < 4; ++e)
                if (j * 4 + e < 14) wbuf[j * 4 + e] = ow[j][e];
#pragma unroll
        for (int t = 0; t < 9; ++t) {
            float dy = bf2f((ushort_t)(wbuf[t] & 0xffffu));
            float dx = bf2f((ushort_t)(wbuf[t] >> 16));
            unsigned mw_ = wbuf[(18 + t) >> 1];
            float mr = ((18 + t) & 1) ? bf2f((ushort_t)(mw_ >> 16)) : bf2f((ushort_t)(mw_ & 0xffffu));
            float mk = 1.f / (1.f + expf(-mr));
            float ys = (float)(py - 1 + t / 3) + dy;
            float xs = (float)(pxx - 1 + t % 3) + dx;
            float y0f = floorf(ys), x0f = floorf(xs);
            float wy1 = ys - y0f, wx1 = xs - x0f;
            float wy0 = 1.f - wy1, wx0 = 1.f - wx1;
            int yi = (int)y0f, xi = (int)x0f;
            bool vy0 = (yi >= 0) && (yi < 128), vy1 = (yi + 1 >= 0) && (yi + 1 < 128);
            bool vx0 = (xi >= 0) && (xi < 128), vx1 = (xi + 1 >= 0) && (xi + 1 < 128);
            mw[t][0] = (vy0 && vx0) ? wy0 * wx0 * mk : 0.f;
            mw[t][1] = (vy0 && vx1) ? wy0 * wx1 * mk : 0.f;
            mw[t][2] = (vy1 && vx0) ? wy1 * wx0 * mk : 0.f;
            mw[t][3] = (vy1 && vx1) ? wy1 * wx1 * mk : 0.f;
            int y0c = min(max(yi, 0), 127), y1c = min(max(yi + 1, 0), 127);
            int x0c = min(max(xi, 0), 127), x1c = min(max(xi + 1, 0), 127);
            mc[t] = (unsigned)y0c | ((unsigned)y1c << 8) | ((unsigned)x0c << 16) | ((unsigned)x1c << 24);
        }
    }

    const int w_off = pxl * 32 + ((q ^ ((pxl ^ (pxl >> 2)) & 3)) << 3);
    int a_off[4];
#pragma unroll
    for (int m = 0; m < 4; ++m) {
        int p_ = m * 16 + lo;
        a_off[m] = p_ * 32 + ((hi ^ ((p_ ^ (p_ >> 2)) & 3)) << 3);
    }

    f32x4 acc[4][2];
#pragma unroll
    for (int m = 0; m < 4; ++m)
#pragma unroll
        for (int n = 0; n < 2; ++n) acc[m][n] = (f32x4){0.f, 0.f, 0.f, 0.f};

    uint4v na, nb, nc, nd;

    // ---- prologue: sample (cch=0, own chunk, t=0) into buf 0 ----
    {
        unsigned c = mc[0];
        int yy0 = c & 255, yy1 = (c >> 8) & 255, xx0 = (c >> 16) & 255, xx1 = c >> 24;
        const ushort_t* pc = fb + hc * 32 + q * 8;
        na = *(const uint4v*)(pc + (size_t)((yy0 << 7) + xx0) * 256);
        nb = *(const uint4v*)(pc + (size_t)((yy0 << 7) + xx1) * 256);
        nc = *(const uint4v*)(pc + (size_t)((yy1 << 7) + xx0) * 256);
        nd = *(const uint4v*)(pc + (size_t)((yy1 << 7) + xx1) * 256);
        float sv[8] = {0.f, 0.f, 0.f, 0.f, 0.f, 0.f, 0.f, 0.f};
        corner8(na, mw[0][0], sv); corner8(nb, mw[0][1], sv);
        corner8(nc, mw[0][2], sv); corner8(nd, mw[0][3], sv);
        unsigned pk[4];
#pragma unroll
        for (int j = 0; j < 4; ++j)
            asm("v_cvt_pk_bf16_f32 %0, %1, %2" : "=v"(pk[j]) : "v"(sv[2 * j]), "v"(sv[2 * j + 1]));
        *(uint4v*)&sm.a[0][hc][w_off] = (uint4v){pk[0], pk[1], pk[2], pk[3]};
    }
    __syncthreads();

    // ---- main loop: 36 iters (cch 0..3 x t 0..8), K=64 per iter, 1 barrier/iter ----
    for (int cch = 0; cch < 4; ++cch) {
#pragma unroll
        for (int t = 0; t < 9; ++t) {
            const int cur = (cch + t) & 1;
            const bool last = (cch == 3) && (t == 8);
            const int tn   = (t == 8) ? 0 : t + 1;
            const int cchn = (t == 8) ? cch + 1 : cch;
            // 1. issue next iteration's gathers (own chunk only: 4 loads)
            if (!last) {
                unsigned c = mc[tn];
                int yy0 = c & 255, yy1 = (c >> 8) & 255, xx0 = (c >> 16) & 255, xx1 = c >> 24;
                const ushort_t* pc = fb + (2 * cchn + hc) * 32 + q * 8;
                na = *(const uint4v*)(pc + (size_t)((yy0 << 7) + xx0) * 256);
                nb = *(const uint4v*)(pc + (size_t)((yy0 << 7) + xx1) * 256);
                nc = *(const uint4v*)(pc + (size_t)((yy1 << 7) + xx0) * 256);
                nd = *(const uint4v*)(pc + (size_t)((yy1 << 7) + xx1) * 256);
            }
            // 2. B fragments: wave-unique n-frag pair, both k-chunks
            short8 bfr0[2], bfr1[2];
            {
                const ushort_t* bs0 = wpk + ((size_t)((t * 8 + 2 * cch) * 16 + wv * 2) * 64 + lane) * 8;
#pragma unroll
                for (int n = 0; n < 2; ++n)
                    bfr0[n] = *(const short8*)(bs0 + (size_t)n * 512);
                const ushort_t* bs1 = bs0 + 16 * 512;
#pragma unroll
                for (int n = 0; n < 2; ++n)
                    bfr1[n] = *(const short8*)(bs1 + (size_t)n * 512);
            }
            // 3. MFMA: 4 m-frags x 2 n-frags x 2 k-chunks
#pragma unroll
            for (int m = 0; m < 4; ++m) {
                short8 af0 = *(const short8*)&sm.a[cur][0][a_off[m]];
                short8 af1 = *(const short8*)&sm.a[cur][1][a_off[m]];
#pragma unroll
                for (int n = 0; n < 2; ++n)
                    acc[m][n] = __builtin_amdgcn_mfma_f32_16x16x32_bf16(af0, bfr0[n], acc[m][n], 0, 0, 0);
#pragma unroll
                for (int n = 0; n < 2; ++n)
                    acc[m][n] = __builtin_amdgcn_mfma_f32_16x16x32_bf16(af1, bfr1[n], acc[m][n], 0, 0, 0);
            }
            // 4. combine next gathers, write other LDS buffer
            if (!last) {
                float sv[8] = {0.f, 0.f, 0.f, 0.f, 0.f, 0.f, 0.f, 0.f};
                corner8(na, mw[tn][0], sv); corner8(nb, mw[tn][1], sv);
                corner8(nc, mw[tn][2], sv); corner8(nd, mw[tn][3], sv);
                unsigned pk[4];
#pragma unroll
                for (int j = 0; j < 4; ++j)
                    asm("v_cvt_pk_bf16_f32 %0, %1, %2" : "=v"(pk[j]) : "v"(sv[2 * j]), "v"(sv[2 * j + 1]));
                *(uint4v*)&sm.a[cur ^ 1][hc][w_off] = (uint4v){pk[0], pk[1], pk[2], pk[3]};
            }
            __syncthreads();
        }
    }

    // ---- epilogue: bias + relu -> NHWC bf16; wave wv owns oc 32*wv..32*wv+31 ----
    float br[2];
#pragma unroll
    for (int n = 0; n < 2; ++n) br[n] = bias[wv * 32 + n * 16 + lo];
#pragma unroll
    for (int p = 0; p < 4; ++p) {
#pragma unroll
        for (int n = 0; n < 2; ++n)
#pragma unroll
            for (int r = 0; r < 4; ++r)
                sm.e[(hi * 4 + r) * 264 + wv * 32 + n * 16 + lo] = fmaxf(acc[p][n][r] + br[n], 0.f);
        __syncthreads();
        {
            int pl = tid >> 5, ch = tid & 31;
            f32x4 v0 = *(const f32x4*)&sm.e[pl * 264 + ch * 8];
            f32x4 v1 = *(const f32x4*)&sm.e[pl * 264 + ch * 8 + 4];
            short8 s;
#pragma unroll
            for (int jj = 0; jj < 4; ++jj) s[jj] = (short)f2bf(v0[jj]);
#pragma unroll
            for (int jj = 0; jj < 4; ++jj) s[4 + jj] = (short)f2bf(v1[jj]);
            *(short8*)&outp[((size_t)b * 16384 + (size_t)(y0 + p) * 128 + x0 + pl) * 256 + ch * 8] = s;
        }
        __syncthreads();
    }
}

// ---------------- host launch ----------------
extern "C" void kernel_launch(void* const* d_in, const int* in_sizes, int n_in,
                              void* d_out, int out_size, void* d_ws, size_t ws_size,
                              hipStream_t stream) {
    const float* x     = (const float*)d_in[0];
    const float* votes = (const float*)d_in[1];
    const float* w1    = (const float*)d_in[2];
    const float* b1    = (const float*)d_in[3];
    const float* w_off = (const float*)d_in[4];
    const float* b_off = (const float*)d_in[5];
    const float* w_dcn = (const float*)d_in[6];
    const float* b_dcn = (const float*)d_in[7];
    const float* w2    = (const float*)d_in[8];
    const float* b2    = (const float*)d_in[9];
    const float* w3    = (const float*)d_in[10];
    const float* b3    = (const float*)d_in[11];
    const float* w4    = (const float*)d_in[12];
    const float* b4    = (const float*)d_in[13];
    float* outp = (float*)d_out;

    const int B = 2;
    const size_t featN = (size_t)B * 16384 * 256;

    ushort_t* ws   = (ushort_t*)d_ws;
    ushort_t* t1   = ws;
    ushort_t* t2   = t1 + featN;
    ushort_t* aN   = t2 + featN;
    ushort_t* xN   = aN + featN;
    ushort_t* om   = xN + featN;
    ushort_t* wpk1 = om + (size_t)B * 16384 * 32;
    ushort_t* wpkO = wpk1 + 589824;
    ushort_t* wpkD = wpkO + 73728;
    ushort_t* wpk2 = wpkD + 589824;
    ushort_t* wpk3 = wpk2 + 589824;
    ushort_t* zp   = wpk3 + 589824;

    // all prep (weight packs + zero page + NHWC transposes): ONE launch
    prep_all_kernel<<<1189 + 4096, 256, 0, stream>>>(w1, wpk1, w_off, wpkO, w_dcn, wpkD,
                                                     w2, wpk2, w3, wpk3, zp, votes, x, aN, xN);

    dim3 cg16(8, 32, B);
    // conv1: t1 = relu(conv(relu(votes), w1, b1))
    conv_mfma_kernel<16, 256, 1><<<cg16, 512, 0, stream>>>(aN, wpk1, b1, 256, nullptr, t1, zp, nullptr, nullptr, nullptr);
    // conv_off: om = conv(t1, w_off, b_off)
    conv_mfma_kernel<16, 32, 0><<<cg16, 512, 0, stream>>>(t1, wpkO, b_off, 27, nullptr, om, zp, nullptr, nullptr, nullptr);
    // dcn: t2 = relu(dcn(t1, om, w_dcn, b_dcn))  — 512 blocks x 512 threads, 128-VGPR cap
    dcn_mfma_kernel<<<512, 512, 0, stream>>>(t1, om, wpkD, b_dcn, t2);
    // conv2 + fuse: g = (conv(t2, w2) + b2) * x
    conv_mfma_kernel<16, 256, 2><<<cg16, 512, 0, stream>>>(t2, wpk2, b2, 256, xN, aN, zp, nullptr, nullptr, nullptr);
    // conv3 + fused 1x1: out = conv1x1(relu(conv(g, w3, b3)), w4, b4)
    conv_mfma_kernel<16, 256, 3><<<cg16, 512, 0, stream>>>(aN, wpk3, b3, 256, nullptr, nullptr, zp, w4, b4, outp);
}

// Round 20
// 241.159 us; speedup vs baseline: 1.1417x; 1.0812x over previous
//
#include <hip/hip_runtime.h>
#include <math.h>

typedef short short8 __attribute__((ext_vector_type(8)));
typedef float f32x4 __attribute__((ext_vector_type(4)));
typedef unsigned int uint4v __attribute__((ext_vector_type(4)));
typedef unsigned short ushort_t;

__device__ inline ushort_t f2bf(float f) {
    unsigned u = __builtin_bit_cast(unsigned, f);
    u = (u + 0x7fffu + ((u >> 16) & 1u)) >> 16;   // RNE
    return (ushort_t)u;
}
__device__ inline float bf2f(ushort_t u) {
    return __builtin_bit_cast(float, (unsigned)u << 16);
}
__device__ inline void gload_lds16(const ushort_t* g, short* l) {
    __builtin_amdgcn_global_load_lds((const __attribute__((address_space(1))) unsigned int*)g,
                                     (__attribute__((address_space(3))) unsigned int*)l, 16, 0, 0);
}

// ---------------- prep: all weight packs + zero page + both NHWC transposes, ONE launch ----------------
__device__ inline void wpack_body(const float* __restrict__ w, ushort_t* __restrict__ wpk,
                                  int COUT, int NF, int bidLocal, int tid) {
    int T = bidLocal * 256 + tid;
    int lane = T & 63;
    int rest = T >> 6;
    int n = rest % NF;
    int kstep = rest / NF;          // 0..71
    int t = kstep >> 3, cc = kstep & 7;
    int oc = n * 16 + (lane & 15);
    int kk = (lane >> 4) * 8;
    short8 sv;
#pragma unroll
    for (int j = 0; j < 8; ++j) {
        int ci = cc * 32 + kk + j;
        float val = (oc < COUT) ? w[((size_t)oc * 256 + ci) * 9 + t] : 0.f;
        sv[j] = (short)f2bf(val);
    }
    *(short8*)&wpk[(size_t)T * 8] = sv;
}

__global__ __launch_bounds__(256)
void prep_all_kernel(const float* w1, ushort_t* wpk1,
                     const float* w_off, ushort_t* wpkO,
                     const float* w_dcn, ushort_t* wpkD,
                     const float* w2, ushort_t* wpk2,
                     const float* w3, ushort_t* wpk3,
                     ushort_t* zp,
                     const float* __restrict__ votes, const float* __restrict__ x,
                     ushort_t* __restrict__ aN, ushort_t* __restrict__ xN) {
    __shared__ short s[64 * 66];
    int bid = blockIdx.x, tid = threadIdx.x;
    if (bid < 288)       { wpack_body(w1,    wpk1, 256, 16, bid,        tid); return; }
    else if (bid < 324)  { wpack_body(w_off, wpkO, 27,  2,  bid - 288,  tid); return; }
    else if (bid < 612)  { wpack_body(w_dcn, wpkD, 256, 16, bid - 324,  tid); return; }
    else if (bid < 900)  { wpack_body(w2,    wpk2, 256, 16, bid - 612,  tid); return; }
    else if (bid < 1188) { wpack_body(w3,    wpk3, 256, 16, bid - 900,  tid); return; }
    else if (bid == 1188) { zp[tid] = 0; return; }
    // nhwc transpose blocks
    int nb = bid - 1189;                  // 0..4095
    const int px0 = (nb & 255) * 64;
    const int ci0 = ((nb >> 8) & 3) * 64;
    const int z   = nb >> 10;             // 0,1 = votes(relu); 2,3 = x
    const int b   = z & 1;
    const bool doRelu = (z < 2);
    const float* inb = (doRelu ? votes : x) + (size_t)b * 256 * 16384;
    ushort_t* ob = (doRelu ? aN : xN) + (size_t)b * 16384 * 256;
#pragma unroll
    for (int rep = 0; rep < 16; ++rep) {
        int cl = rep * 4 + (tid >> 6);
        int pl = tid & 63;
        float v = inb[(size_t)(ci0 + cl) * 16384 + px0 + pl];
        if (doRelu) v = fmaxf(v, 0.f);
        s[pl * 66 + cl] = (short)f2bf(v);
    }
    __syncthreads();
#pragma unroll
    for (int rep = 0; rep < 2; ++rep) {
        int c = rep * 256 + tid;
        int pl = c >> 3;
        int cl = (c & 7) * 8;
        *(short8*)&ob[(size_t)(px0 + pl) * 256 + ci0 + cl] = *(const short8*)&s[pl * 66 + cl];
    }
}

// ---------------- MFMA implicit-GEMM 3x3 conv, NHWC bf16 in/out (r15-validated) ----------------
// EPI: 0 = bias, 1 = bias+relu, 2 = (bias+v)*x, 3 = bias+relu + fused 1x1 -> out4
template<int TW, int OUTC, int EPI>
__global__ __launch_bounds__(512, 2)
void conv_mfma_kernel(const ushort_t* __restrict__ in, const ushort_t* __restrict__ wpk,
                      const float* __restrict__ bias, int coutReal,
                      const ushort_t* __restrict__ xin, ushort_t* __restrict__ outp,
                      const ushort_t* __restrict__ zp,
                      const float* __restrict__ w4g, const float* __restrict__ b4g,
                      float* __restrict__ out4)
{
    constexpr int NF = OUTC / 16;
    constexpr int NN = (NF < 4) ? NF : 4;
    constexpr int HWD = TW + 2;
    constexpr int HPX = 6 * HWD;
    constexpr int ROUNDS = (HPX * 4 + 511) / 512;
    constexpr int MW  = TW / 16;
    constexpr int MPW = TW / 8;
    constexpr int PITCH = OUTC + 4;
    union SM { short a[2][ROUNDS * 512 * 8]; float e[TW * PITCH]; };
    __shared__ __align__(16) SM sm;

    const int tid  = threadIdx.x;
    const int lane = tid & 63;
    const int wv   = tid >> 6;
    const int hi   = lane >> 4;
    const int lo   = lane & 15;
    const int pxg  = wv & 1;
    const int wn   = wv >> 1;
    const int wnu  = __builtin_amdgcn_readfirstlane(wn);
    const int x0 = blockIdx.x * TW;
    const int y0 = blockIdx.y * 4;
    const int b  = blockIdx.z;
    const ushort_t* inb = in + (size_t)b * 16384 * 256;

    const ushort_t* sptr[ROUNDS];
    int sstep[ROUNDS];
#pragma unroll
    for (int r = 0; r < ROUNDS; ++r) {
        int g = r * 512 + tid;
        int px = g >> 2, slot = g & 3;
        int hy = px / HWD, hx = px - hy * HWD;
        int gy = y0 - 1 + hy, gx = x0 - 1 + hx;
        bool ok = (px < HPX) && ((unsigned)gy < 128u) && ((unsigned)gx < 128u);
        int kk = (px ^ (px >> 2)) & 3;
        sptr[r] = ok ? (inb + (size_t)((gy << 7) + gx) * 256 + ((slot ^ kk) << 3))
                     : (zp + (slot << 3));
        sstep[r] = ok ? 32 : 0;
    }

    int pxh_base[MPW];
#pragma unroll
    for (int m = 0; m < MPW; ++m)
        pxh_base[m] = (2 * pxg + m / MW) * HWD + (m % MW) * 16 + lo;

    f32x4 acc[MPW][NN];
#pragma unroll
    for (int m = 0; m < MPW; ++m)
#pragma unroll
        for (int n = 0; n < NN; ++n) acc[m][n] = (f32x4){0.f, 0.f, 0.f, 0.f};

#pragma unroll
    for (int r = 0; r < ROUNDS; ++r)
        gload_lds16(sptr[r], &sm.a[0][(r * 512 + wv * 64) * 8]);
    __syncthreads();

    for (int cc = 0; cc < 8; ++cc) {
        const int buf = cc & 1;
        if (cc < 7) {
#pragma unroll
            for (int r = 0; r < ROUNDS; ++r)
                gload_lds16(sptr[r] + (size_t)(cc + 1) * sstep[r],
                            &sm.a[buf ^ 1][(r * 512 + wv * 64) * 8]);
        }
        if (NF >= 4 || wnu == 0) {
#pragma unroll
            for (int t = 0; t < 9; ++t) {
                const int ky = t / 3, kx = t % 3;
                short8 bf[NN];
#pragma unroll
                for (int n = 0; n < NN; ++n)
                    bf[n] = *(const short8*)&wpk[((size_t)((t * 8 + cc) * NF + wnu * NN + n) * 64 + lane) * 8];
                short8 af[MPW];
#pragma unroll
                for (int m = 0; m < MPW; ++m) {
                    int ph = pxh_base[m] + ky * HWD + kx;
                    int off = ph * 32 + ((hi ^ ((ph ^ (ph >> 2)) & 3)) << 3);
                    af[m] = *(const short8*)&sm.a[buf][off];
                }
#pragma unroll
                for (int m = 0; m < MPW; ++m)
#pragma unroll
                    for (int n = 0; n < NN; ++n)
                        acc[m][n] = __builtin_amdgcn_mfma_f32_16x16x32_bf16(af[m], bf[n], acc[m][n], 0, 0, 0);
            }
        }
        __syncthreads();
    }

    float br[NN];
#pragma unroll
    for (int n = 0; n < NN; ++n) {
        int oc = wn * (16 * NN) + n * 16 + lo;
        br[n] = (oc < coutReal) ? bias[oc] : 0.f;
    }
    const size_t obase = ((size_t)b * 16384 + (size_t)y0 * 128 + x0) * OUTC;
#pragma unroll
    for (int p = 0; p < 4; ++p) {
        if (pxg == (p >> 1) && (NF >= 4 || wnu == 0)) {
#pragma unroll
            for (int mm = 0; mm < MW; ++mm) {
                int m = (p & 1) * MW + mm;
#pragma unroll
                for (int n = 0; n < NN; ++n)
#pragma unroll
                    for (int r = 0; r < 4; ++r) {
                        int col = mm * 16 + hi * 4 + r;
                        float v = acc[m][n][r] + br[n];
                        if (EPI == 1 || EPI == 3) v = fmaxf(v, 0.f);
                        sm.e[col * PITCH + wn * (16 * NN) + n * 16 + lo] = v;
                    }
            }
        }
        __syncthreads();
        if constexpr (EPI == 3) {
            int col = tid >> 5;
            int ch  = tid & 31;
            f32x4 v0 = *(const f32x4*)&sm.e[col * PITCH + ch * 8];
            f32x4 v1 = *(const f32x4*)&sm.e[col * PITCH + ch * 8 + 4];
            float4 wa0 = *(const float4*)&w4g[ch * 8];
            float4 wa1 = *(const float4*)&w4g[ch * 8 + 4];
            float4 wb0 = *(const float4*)&w4g[256 + ch * 8];
            float4 wb1 = *(const float4*)&w4g[256 + ch * 8 + 4];
            float a0 = v0[0] * wa0.x + v0[1] * wa0.y + v0[2] * wa0.z + v0[3] * wa0.w
                     + v1[0] * wa1.x + v1[1] * wa1.y + v1[2] * wa1.z + v1[3] * wa1.w;
            float a1 = v0[0] * wb0.x + v0[1] * wb0.y + v0[2] * wb0.z + v0[3] * wb0.w
                     + v1[0] * wb1.x + v1[1] * wb1.y + v1[2] * wb1.z + v1[3] * wb1.w;
#pragma unroll
            for (int s = 16; s >= 1; s >>= 1) {
                a0 += __shfl_xor(a0, s);
                a1 += __shfl_xor(a1, s);
            }
            if (ch == 0) {
                size_t o = (size_t)b * 2 * 16384 + (size_t)(y0 + p) * 128 + x0 + col;
                out4[o]         = a0 + b4g[0];
                out4[o + 16384] = a1 + b4g[1];
            }
        } else {
            constexpr int CHUNKS = TW * OUTC / 8;
            for (int c = tid; c < CHUNKS; c += 512) {
                int col = c / (OUTC / 8);
                int ch = c % (OUTC / 8);
                f32x4 v0 = *(const f32x4*)&sm.e[col * PITCH + ch * 8];
                f32x4 v1 = *(const f32x4*)&sm.e[col * PITCH + ch * 8 + 4];
                size_t gidx = obase + ((size_t)p * 128 + col) * OUTC + ch * 8;
                if (EPI == 2) {
                    uint4v xu = *(const uint4v*)&xin[gidx];
#pragma unroll
                    for (int j = 0; j < 4; ++j) {
                        float xa = bf2f((ushort_t)(xu[j] & 0xffffu));
                        float xb = __builtin_bit_cast(float, xu[j] & 0xffff0000u);
                        if (j < 2) { v0[2 * j] *= xa; v0[2 * j + 1] *= xb; }
                        else       { v1[2 * (j - 2)] *= xa; v1[2 * (j - 2) + 1] *= xb; }
                    }
                }
                short8 s;
#pragma unroll
                for (int j = 0; j < 4; ++j) s[j] = (short)f2bf(v0[j]);
#pragma unroll
                for (int j = 0; j < 4; ++j) s[4 + j] = (short)f2bf(v1[j]);
                *(short8*)&outp[gidx] = s;
            }
        }
        __syncthreads();
    }
}

// ---------------- DCN v2 (r13-exact, validated ~72 us): 16x4 px x 256 oc, 4-lane/px gathers ----------------
__device__ inline void corner8(uint4v u, float w, float* sv) {
#pragma unroll
    for (int j = 0; j < 4; ++j) {
        unsigned a = u[j];
        sv[2 * j]     = fmaf(w, __builtin_bit_cast(float, a << 16), sv[2 * j]);
        sv[2 * j + 1] = fmaf(w, __builtin_bit_cast(float, a & 0xffff0000u), sv[2 * j + 1]);
    }
}

__global__ __launch_bounds__(256, 2)
void dcn_mfma_kernel(const ushort_t* __restrict__ ft, const ushort_t* __restrict__ omt,
                     const ushort_t* __restrict__ wpk, const float* __restrict__ bias,
                     ushort_t* __restrict__ outp)
{
    union SM { short a[2][2][2048]; float e[16 * 264]; };
    __shared__ __align__(16) SM sm;

    const int tid  = threadIdx.x;
    const int lane = tid & 63;
    const int wv   = tid >> 6;
    const int hi   = lane >> 4;
    const int lo   = lane & 15;
    const int bid  = blockIdx.x;
    const int tile = (bid & 7) * 64 + (bid >> 3);
    const int b    = tile >> 8;
    const int rem  = tile & 255;
    const int y0   = (rem >> 3) * 4;
    const int x0   = (rem & 7) * 16;
    const ushort_t* fb = ft + (size_t)b * 16384 * 256;

    const int pxl = (wv << 4) | (lane >> 2);   // 4 consecutive lanes share a pixel
    const int q   = lane & 3;                  // ci slice (8 of 32)

    float mw[9][4];
    unsigned mc[9];
    {
        const int py = y0 + (pxl >> 4), pxx = x0 + (pxl & 15);
        const ushort_t* omp = omt + ((size_t)b * 16384 + py * 128 + pxx) * 32;
        uint4v ow[4];
#pragma unroll
        for (int j = 0; j < 4; ++j) ow[j] = *(const uint4v*)(omp + j * 8);
        unsigned wbuf[14];
#pragma unroll
        for (int j = 0; j < 4; ++j)
#pragma unroll
            for (int e = 0; e < 4; ++e)
                if (j * 4 + e < 14) wbuf[j * 4 + e] = ow[j][e];
#pragma unroll
        for (int t = 0; t < 9; ++t) {
            float dy = bf2f((ushort_t)(wbuf[t] & 0xffffu));
            float dx = bf2f((ushort_t)(wbuf[t] >> 16));
            unsigned mw_ = wbuf[(18 + t) >> 1];
            float mr = ((18 + t) & 1) ? bf2f((ushort_t)(mw_ >> 16)) : bf2f((ushort_t)(mw_ & 0xffffu));
            float mk = 1.f / (1.f + expf(-mr));
            float ys = (float)(py - 1 + t / 3) + dy;
            float xs = (float)(pxx - 1 + t % 3) + dx;
            float y0f = floorf(ys), x0f = floorf(xs);
            float wy1 = ys - y0f, wx1 = xs - x0f;
            float wy0 = 1.f - wy1, wx0 = 1.f - wx1;
            int yi = (int)y0f, xi = (int)x0f;
            bool vy0 = (yi >= 0) && (yi < 128), vy1 = (yi + 1 >= 0) && (yi + 1 < 128);
            bool vx0 = (xi >= 0) && (xi < 128), vx1 = (xi + 1 >= 0) && (xi + 1 < 128);
            mw[t][0] = (vy0 && vx0) ? wy0 * wx0 * mk : 0.f;
            mw[t][1] = (vy0 && vx1) ? wy0 * wx1 * mk : 0.f;
            mw[t][2] = (vy1 && vx0) ? wy1 * wx0 * mk : 0.f;
            mw[t][3] = (vy1 && vx1) ? wy1 * wx1 * mk : 0.f;
            int y0c = min(max(yi, 0), 127), y1c = min(max(yi + 1, 0), 127);
            int x0c = min(max(xi, 0), 127), x1c = min(max(xi + 1, 0), 127);
            mc[t] = (unsigned)y0c | ((unsigned)y1c << 8) | ((unsigned)x0c << 16) | ((unsigned)x1c << 24);
        }
    }

    const int w_off = pxl * 32 + ((q ^ ((pxl ^ (pxl >> 2)) & 3)) << 3);
    int a_off[4];
#pragma unroll
    for (int m = 0; m < 4; ++m) {
        int p_ = m * 16 + lo;
        a_off[m] = p_ * 32 + ((hi ^ ((p_ ^ (p_ >> 2)) & 3)) << 3);
    }

    f32x4 acc[4][4];
#pragma unroll
    for (int m = 0; m < 4; ++m)
#pragma unroll
        for (int n = 0; n < 4; ++n) acc[m][n] = (f32x4){0.f, 0.f, 0.f, 0.f};

    uint4v n0a, n0b, n0c, n0d;
    uint4v n1a, n1b, n1c, n1d;

    {
        unsigned c = mc[0];
        int yy0 = c & 255, yy1 = (c >> 8) & 255, xx0 = (c >> 16) & 255, xx1 = c >> 24;
        size_t o00 = (size_t)((yy0 << 7) + xx0) * 256, o01 = (size_t)((yy0 << 7) + xx1) * 256;
        size_t o10 = (size_t)((yy1 << 7) + xx0) * 256, o11 = (size_t)((yy1 << 7) + xx1) * 256;
#pragma unroll
        for (int h = 0; h < 2; ++h) {
            const ushort_t* pc = fb + h * 32 + q * 8;
            uint4v g0 = *(const uint4v*)(pc + o00);
            uint4v g1 = *(const uint4v*)(pc + o01);
            uint4v g2 = *(const uint4v*)(pc + o10);
            uint4v g3 = *(const uint4v*)(pc + o11);
            float sv[8] = {0.f, 0.f, 0.f, 0.f, 0.f, 0.f, 0.f, 0.f};
            corner8(g0, mw[0][0], sv); corner8(g1, mw[0][1], sv);
            corner8(g2, mw[0][2], sv); corner8(g3, mw[0][3], sv);
            unsigned pk[4];
#pragma unroll
            for (int j = 0; j < 4; ++j)
                asm("v_cvt_pk_bf16_f32 %0, %1, %2" : "=v"(pk[j]) : "v"(sv[2 * j]), "v"(sv[2 * j + 1]));
            *(uint4v*)&sm.a[0][h][w_off] = (uint4v){pk[0], pk[1], pk[2], pk[3]};
        }
    }
    __syncthreads();

    for (int cch = 0; cch < 4; ++cch) {
#pragma unroll
        for (int t = 0; t < 9; ++t) {
            const int cur = (cch + t) & 1;
            const bool last = (cch == 3) && (t == 8);
            const int tn   = (t == 8) ? 0 : t + 1;
            const int cchn = (t == 8) ? cch + 1 : cch;
            if (!last) {
                unsigned c = mc[tn];
                int yy0 = c & 255, yy1 = (c >> 8) & 255, xx0 = (c >> 16) & 255, xx1 = c >> 24;
                size_t o00 = (size_t)((yy0 << 7) + xx0) * 256, o01 = (size_t)((yy0 << 7) + xx1) * 256;
                size_t o10 = (size_t)((yy1 << 7) + xx0) * 256, o11 = (size_t)((yy1 << 7) + xx1) * 256;
                const ushort_t* pc0 = fb + (2 * cchn) * 32 + q * 8;
                n0a = *(const uint4v*)(pc0 + o00);
                n0b = *(const uint4v*)(pc0 + o01);
                n0c = *(const uint4v*)(pc0 + o10);
                n0d = *(const uint4v*)(pc0 + o11);
                const ushort_t* pc1 = pc0 + 32;
                n1a = *(const uint4v*)(pc1 + o00);
                n1b = *(const uint4v*)(pc1 + o01);
                n1c = *(const uint4v*)(pc1 + o10);
                n1d = *(const uint4v*)(pc1 + o11);
            }
            short8 bfr0[4], bfr1[4];
            {
                const ushort_t* bs0 = wpk + ((size_t)((t * 8 + 2 * cch) * 16 + wv * 4) * 64 + lane) * 8;
#pragma unroll
                for (int n = 0; n < 4; ++n)
                    bfr0[n] = *(const short8*)(bs0 + (size_t)n * 512);
                const ushort_t* bs1 = bs0 + 16 * 512;
#pragma unroll
                for (int n = 0; n < 4; ++n)
                    bfr1[n] = *(const short8*)(bs1 + (size_t)n * 512);
            }
#pragma unroll
            for (int m = 0; m < 4; ++m) {
                short8 af0 = *(const short8*)&sm.a[cur][0][a_off[m]];
                short8 af1 = *(const short8*)&sm.a[cur][1][a_off[m]];
#pragma unroll
                for (int n = 0; n < 4; ++n)
                    acc[m][n] = __builtin_amdgcn_mfma_f32_16x16x32_bf16(af0, bfr0[n], acc[m][n], 0, 0, 0);
#pragma unroll
                for (int n = 0; n < 4; ++n)
                    acc[m][n] = __builtin_amdgcn_mfma_f32_16x16x32_bf16(af1, bfr1[n], acc[m][n], 0, 0, 0);
            }
            if (!last) {
                {
                    float sv[8] = {0.f, 0.f, 0.f, 0.f, 0.f, 0.f, 0.f, 0.f};
                    corner8(n0a, mw[tn][0], sv); corner8(n0b, mw[tn][1], sv);
                    corner8(n0c, mw[tn][2], sv); corner8(n0d, mw[tn][3], sv);
                    unsigned pk[4];
#pragma unroll
                    for (int j = 0; j < 4; ++j)
                        asm("v_cvt_pk_bf16_f32 %0, %1, %2" : "=v"(pk[j]) : "v"(sv[2 * j]), "v"(sv[2 * j + 1]));
                    *(uint4v*)&sm.a[cur ^ 1][0][w_off] = (uint4v){pk[0], pk[1], pk[2], pk[3]};
                }
                {
                    float sv[8] = {0.f, 0.f, 0.f, 0.f, 0.f, 0.f, 0.f, 0.f};
                    corner8(n1a, mw[tn][0], sv); corner8(n1b, mw[tn][1], sv);
                    corner8(n1c, mw[tn][2], sv); corner8(n1d, mw[tn][3], sv);
                    unsigned pk[4];
#pragma unroll
                    for (int j = 0; j < 4; ++j)
                        asm("v_cvt_pk_bf16_f32 %0, %1, %2" : "=v"(pk[j]) : "v"(sv[2 * j]), "v"(sv[2 * j + 1]));
                    *(uint4v*)&sm.a[cur ^ 1][1][w_off] = (uint4v){pk[0], pk[1], pk[2], pk[3]};
                }
            }
            __syncthreads();
        }
    }

    float br[4];
#pragma unroll
    for (int n = 0; n < 4; ++n) br[n] = bias[wv * 64 + n * 16 + lo];
#pragma unroll
    for (int p = 0; p < 4; ++p) {
#pragma unroll
        for (int n = 0; n < 4; ++n)
#pragma unroll
            for (int r = 0; r < 4; ++r)
                sm.e[(hi * 4 + r) * 264 + wv * 64 + n * 16 + lo] = fmaxf(acc[p][n][r] + br[n], 0.f);
        __syncthreads();
#pragma unroll
        for (int j = 0; j < 2; ++j) {
            int c2 = j * 256 + tid;
            int pl = c2 >> 5, ch = c2 & 31;
            f32x4 v0 = *(const f32x4*)&sm.e[pl * 264 + ch * 8];
            f32x4 v1 = *(const f32x4*)&sm.e[pl * 264 + ch * 8 + 4];
            short8 s;
#pragma unroll
            for (int jj = 0; jj < 4; ++jj) s[jj] = (short)f2bf(v0[jj]);
#pragma unroll
            for (int jj = 0; jj < 4; ++jj) s[4 + jj] = (short)f2bf(v1[jj]);
            *(short8*)&outp[((size_t)b * 16384 + (size_t)(y0 + p) * 128 + x0 + pl) * 256 + ch * 8] = s;
        }
        __syncthreads();
    }
}

// ---------------- host launch ----------------
extern "C" void kernel_launch(void* const* d_in, const int* in_sizes, int n_in,
                              void* d_out, int out_size, void* d_ws, size_t ws_size,
                              hipStream_t stream) {
    const float* x     = (const float*)d_in[0];
    const float* votes = (const float*)d_in[1];
    const float* w1    = (const float*)d_in[2];
    const float* b1    = (const float*)d_in[3];
    const float* w_off = (const float*)d_in[4];
    const float* b_off = (const float*)d_in[5];
    const float* w_dcn = (const float*)d_in[6];
    const float* b_dcn = (const float*)d_in[7];
    const float* w2    = (const float*)d_in[8];
    const float* b2    = (const float*)d_in[9];
    const float* w3    = (const float*)d_in[10];
    const float* b3    = (const float*)d_in[11];
    const float* w4    = (const float*)d_in[12];
    const float* b4    = (const float*)d_in[13];
    float* outp = (float*)d_out;

    const int B = 2;
    const size_t featN = (size_t)B * 16384 * 256;

    ushort_t* ws   = (ushort_t*)d_ws;
    ushort_t* t1   = ws;
    ushort_t* t2   = t1 + featN;
    ushort_t* aN   = t2 + featN;
    ushort_t* xN   = aN + featN;
    ushort_t* om   = xN + featN;
    ushort_t* wpk1 = om + (size_t)B * 16384 * 32;
    ushort_t* wpkO = wpk1 + 589824;
    ushort_t* wpkD = wpkO + 73728;
    ushort_t* wpk2 = wpkD + 589824;
    ushort_t* wpk3 = wpk2 + 589824;
    ushort_t* zp   = wpk3 + 589824;

    // all prep (weight packs + zero page + NHWC transposes): ONE launch
    prep_all_kernel<<<1189 + 4096, 256, 0, stream>>>(w1, wpk1, w_off, wpkO, w_dcn, wpkD,
                                                     w2, wpk2, w3, wpk3, zp, votes, x, aN, xN);

    dim3 cg16(8, 32, B);
    // conv1: t1 = relu(conv(relu(votes), w1, b1))
    conv_mfma_kernel<16, 256, 1><<<cg16, 512, 0, stream>>>(aN, wpk1, b1, 256, nullptr, t1, zp, nullptr, nullptr, nullptr);
    // conv_off: om = conv(t1, w_off, b_off)
    conv_mfma_kernel<16, 32, 0><<<cg16, 512, 0, stream>>>(t1, wpkO, b_off, 27, nullptr, om, zp, nullptr, nullptr, nullptr);
    // dcn: t2 = relu(dcn(t1, om, w_dcn, b_dcn))
    dcn_mfma_kernel<<<512, 256, 0, stream>>>(t1, om, wpkD, b_dcn, t2);
    // conv2 + fuse: g = (conv(t2, w2) + b2) * x
    conv_mfma_kernel<16, 256, 2><<<cg16, 512, 0, stream>>>(t2, wpk2, b2, 256, xN, aN, zp, nullptr, nullptr, nullptr);
    // conv3 + fused 1x1: out = conv1x1(relu(conv(g, w3, b3)), w4, b4)
    conv_mfma_kernel<16, 256, 3><<<cg16, 512, 0, stream>>>(aN, wpk3, b3, 256, nullptr, nullptr, zp, w4, b4, outp);
}